// Round 5
// baseline (637.429 us; speedup 1.0000x reference)
//
#include <hip/hip_runtime.h>
#include <hip/hip_bf16.h>
#include <cstdint>
#include <cfloat>

#define F 16
#define B 4096
#define D 256
#define K 1024

typedef __attribute__((ext_vector_type(8))) short bf16x8;
typedef __attribute__((ext_vector_type(4))) float f32x4;

// ---- workspace layout (bytes) ----
#define WHT_OFF  0u            // F*K*D bf16 transposed [f][k][d] = 8388608
#define WLT_OFF  8388608u
#define WT_OFF   16777216u     // F*K*D fp32 transposed = 16777216
#define WSQ_OFF  33554432u     // F*K fp32
#define TOP2_OFF 33619968u     // F*B float4 {v1,i1,v2,i2} = 1 MB
#define LOSS_OFF 34668544u

// ---------------- init: zero wsq + loss ----------------
__global__ void init_kernel(float* __restrict__ wsq, double* __restrict__ lossAcc) {
    int i = blockIdx.x * 256 + threadIdx.x;
    if (i < F * K) wsq[i] = 0.f;
    if (i == 0) *lossAcc = 0.0;
}

// ------- transpose w -> wt fp32 [f][k][d] + bf16 hi/lo + fused ||w_k||^2 -------
__global__ void transpose_split_w(const float* __restrict__ w, float* __restrict__ wt,
                                  ushort* __restrict__ whT, ushort* __restrict__ wlT,
                                  float* __restrict__ wsq) {
    __shared__ float sd[32][33];
    int f  = blockIdx.z;
    int k0 = blockIdx.x * 32;
    int d0 = blockIdx.y * 32;
    const float* wf = w + (size_t)f * D * K;
    size_t obase = (size_t)f * K * D;
    int tx = threadIdx.x, ty = threadIdx.y;
#pragma unroll
    for (int i = 0; i < 4; ++i) {
        int d = ty + i * 8;
        sd[d][tx] = wf[(size_t)(d0 + d) * K + (k0 + tx)];
    }
    __syncthreads();
#pragma unroll
    for (int i = 0; i < 4; ++i) {
        int k = ty + i * 8;
        float v = sd[tx][k];
        size_t o = obase + (size_t)(k0 + k) * D + (d0 + tx);
        wt[o] = v;
        __hip_bfloat16 hb = __float2bfloat16(v);
        float hf = __bfloat162float(hb);
        __hip_bfloat16 lb = __float2bfloat16(v - hf);
        whT[o] = *(ushort*)&hb;
        wlT[o] = *(ushort*)&lb;
        float p = v * v;
#pragma unroll
        for (int off = 1; off < 32; off <<= 1) p += __shfl_xor(p, off);
        if (tx == 0) atomicAdd(&wsq[f * K + k0 + k], p);
    }
}

// ---------------- MFMA split-bf16 GEMM + top-2, barrier-free K-loop ----------------
// A (64 rows, full D, h+l) resident in LDS seg-major: Ah [0,16384) Al [16384,32768) ushorts.
// W fragments loaded global->VGPR per wave (16B each, one consumer) -> no barriers.
__global__ __launch_bounds__(512, 4) void gemm_mfma_top2(
        const float* __restrict__ x,
        const ushort* __restrict__ whT, const ushort* __restrict__ wlT,
        const float* __restrict__ wsq, float4* __restrict__ top2v)
{
    __shared__ ushort lds[32768];   // 64 KiB -> 2 blocks/CU
    const int bid  = blockIdx.x;
    const int f    = bid >> 6;             // 64 consecutive blocks share f (W L2-hot)
    const int m0   = (bid & 63) * 64;
    const int tid  = threadIdx.x;
    const int lane = tid & 63;
    const int wave = tid >> 6;             // 0..7
    const int mw   = wave >> 2;            // 0..1 : 32-row half
    const int nw   = wave & 3;             // 0..3 : 32-col quarter of the 128-chunk
    const int quad = lane >> 4, l15 = lane & 15;

    const float*  xb  = x   + ((size_t)f * B + m0) * D;
    const ushort* whb = whT + (size_t)f * K * D;
    const ushort* wlb = wlT + (size_t)f * K * D;

    // ---- prologue: read x fp32, split to bf16 h/l, store seg-major A to LDS
    {
        int row = tid & 63;
        int c4b = tid >> 6;                // 0..7
#pragma unroll
        for (int i = 0; i < 8; ++i) {
            int c4 = c4b + i * 8;          // 0..63 float4 within row
            float4 v = ((const float4*)xb)[row * 64 + c4];
            ushort4 h4, l4;
#pragma unroll
            for (int j = 0; j < 4; ++j) {
                float fv = ((const float*)&v)[j];
                __hip_bfloat16 hb = __float2bfloat16(fv);
                float hf = __bfloat162float(hb);
                __hip_bfloat16 lb = __float2bfloat16(fv - hf);
                ((ushort*)&h4)[j] = *(ushort*)&hb;
                ((ushort*)&l4)[j] = *(ushort*)&lb;
            }
            int seg = c4 >> 1, half = c4 & 1;
            int off = (seg * 64 + row) * 8 + half * 4;
            *(ushort4*)(lds + off)         = h4;
            *(ushort4*)(lds + 16384 + off) = l4;
        }
    }
    __syncthreads();   // the ONLY barrier before the merge

    float v1[8], v2[8];
    int   i1[8], i2[8];
#pragma unroll
    for (int s = 0; s < 8; ++s) {
        v1[s] = FLT_MAX; v2[s] = FLT_MAX; i1[s] = 0x7fffffff; i2[s] = 0x7fffffff;
    }

    for (int n0 = 0; n0 < K; n0 += 128) {
        f32x4 acc[2][2];
#pragma unroll
        for (int mt = 0; mt < 2; ++mt)
#pragma unroll
            for (int nt = 0; nt < 2; ++nt)
                acc[mt][nt] = (f32x4){0.f, 0.f, 0.f, 0.f};

        // per-wave W bases: n = n0 + nw*32 + nt*16 + l15, frag at d = d0 + quad*8
        const ushort* wh0 = whb + (size_t)(n0 + nw * 32 + l15) * D + quad * 8;
        const ushort* wh1 = wh0 + 16 * D;
        const ushort* wl0 = wlb + (size_t)(n0 + nw * 32 + l15) * D + quad * 8;
        const ushort* wl1 = wl0 + 16 * D;

#pragma unroll
        for (int ks = 0; ks < 8; ++ks) {
            const int dofs = ks * 32;     // element offset (fits imm offset field x2B)
            bf16x8 bh0 = *(const bf16x8*)(wh0 + dofs);
            bf16x8 bl0 = *(const bf16x8*)(wl0 + dofs);
            bf16x8 bh1 = *(const bf16x8*)(wh1 + dofs);
            bf16x8 bl1 = *(const bf16x8*)(wl1 + dofs);
            bf16x8 ah[2], al[2];
#pragma unroll
            for (int mt = 0; mt < 2; ++mt) {
                int off = ((ks * 4 + quad) * 64 + mw * 32 + mt * 16 + l15) * 8;
                ah[mt] = *(const bf16x8*)(lds + off);
                al[mt] = *(const bf16x8*)(lds + 16384 + off);
            }
#pragma unroll
            for (int mt = 0; mt < 2; ++mt) {
                acc[mt][0] = __builtin_amdgcn_mfma_f32_16x16x32_bf16(ah[mt], bh0, acc[mt][0], 0, 0, 0);
                acc[mt][0] = __builtin_amdgcn_mfma_f32_16x16x32_bf16(ah[mt], bl0, acc[mt][0], 0, 0, 0);
                acc[mt][0] = __builtin_amdgcn_mfma_f32_16x16x32_bf16(al[mt], bh0, acc[mt][0], 0, 0, 0);
                acc[mt][1] = __builtin_amdgcn_mfma_f32_16x16x32_bf16(ah[mt], bh1, acc[mt][1], 0, 0, 0);
                acc[mt][1] = __builtin_amdgcn_mfma_f32_16x16x32_bf16(ah[mt], bl1, acc[mt][1], 0, 0, 0);
                acc[mt][1] = __builtin_amdgcn_mfma_f32_16x16x32_bf16(al[mt], bh1, acc[mt][1], 0, 0, 0);
            }
        }

        // epilogue: fold 128-column chunk into per-lane top-2
#pragma unroll
        for (int nt = 0; nt < 2; ++nt) {
            int ng = n0 + nw * 32 + nt * 16 + l15;
            float wq = wsq[f * K + ng];
#pragma unroll
            for (int mt = 0; mt < 2; ++mt) {
#pragma unroll
                for (int r = 0; r < 4; ++r) {
                    int s = mt * 4 + r;
                    float sc = fmaf(-2.f, acc[mt][nt][r], wq);
                    if (sc < v1[s]) { v2[s] = v1[s]; i2[s] = i1[s]; v1[s] = sc; i1[s] = ng; }
                    else if (sc < v2[s]) { v2[s] = sc; i2[s] = ng; }
                }
            }
        }
    }

    // cross-lane merge among the 16 l15 lanes (fixed quad)
#pragma unroll
    for (int s = 0; s < 8; ++s) {
#pragma unroll
        for (int off = 1; off < 16; off <<= 1) {
            float ov1 = __shfl_xor(v1[s], off);
            int   oi1 = __shfl_xor(i1[s], off);
            float ov2 = __shfl_xor(v2[s], off);
            int   oi2 = __shfl_xor(i2[s], off);
            bool sw = (ov1 < v1[s]) || (ov1 == v1[s] && oi1 < i1[s]);
            float a1 = sw ? ov1 : v1[s]; int a1i = sw ? oi1 : i1[s];
            float b1 = sw ? v1[s] : ov1; int b1i = sw ? i1[s] : oi1;
            float a2 = sw ? ov2 : v2[s]; int a2i = sw ? oi2 : i2[s];
            bool rp = (b1 < a2) || (b1 == a2 && b1i < a2i);
            v1[s] = a1;            i1[s] = a1i;
            v2[s] = rp ? b1 : a2;  i2[s] = rp ? b1i : a2i;
        }
    }

    // cross-wave (nw 0..3) merge via LDS (A region reusable after barrier)
    __syncthreads();
    float4* mrg = (float4*)lds;            // [64 rows][4 nw] float4
    if (l15 == 0) {
#pragma unroll
        for (int mt = 0; mt < 2; ++mt)
#pragma unroll
            for (int r = 0; r < 4; ++r) {
                int s = mt * 4 + r;
                int rl = mw * 32 + mt * 16 + quad * 4 + r;
                mrg[rl * 4 + nw] = make_float4(v1[s], __int_as_float(i1[s]),
                                               v2[s], __int_as_float(i2[s]));
            }
    }
    __syncthreads();
    if (nw == 0 && l15 == 0) {
#pragma unroll
        for (int mt = 0; mt < 2; ++mt)
#pragma unroll
            for (int r = 0; r < 4; ++r) {
                int s = mt * 4 + r;
                int rl = mw * 32 + mt * 16 + quad * 4 + r;
                float bv1 = v1[s], bv2 = v2[s];
                int   bi1 = i1[s], bi2 = i2[s];
#pragma unroll
                for (int q = 1; q < 4; ++q) {
                    float4 tq = mrg[rl * 4 + q];
                    float ov1 = tq.x, ov2 = tq.z;
                    int   oi1 = __float_as_int(tq.y), oi2 = __float_as_int(tq.w);
                    bool sw = (ov1 < bv1) || (ov1 == bv1 && oi1 < bi1);
                    float a1 = sw ? ov1 : bv1; int a1i = sw ? oi1 : bi1;
                    float b1 = sw ? bv1 : ov1; int b1i = sw ? bi1 : oi1;
                    float a2 = sw ? ov2 : bv2; int a2i = sw ? oi2 : bi2;
                    bool rp = (b1 < a2) || (b1 == a2 && b1i < a2i);
                    bv1 = a1; bi1 = a1i;
                    bv2 = rp ? b1 : a2; bi2 = rp ? b1i : a2i;
                }
                top2v[(size_t)f * B + m0 + rl] =
                    make_float4(bv1, __int_as_float(bi1), bv2, __int_as_float(bi2));
            }
    }
}

// -------- fp64 refine + gather + loss; skip 2nd gather when gap is safe --------
__global__ __launch_bounds__(256) void refine_gather(
        const float* __restrict__ x, const float* __restrict__ wt,
        const float4* __restrict__ top2v, float* __restrict__ out,
        double* __restrict__ lossAcc) {
    __shared__ double lpart[4];
    int tid  = threadIdx.x;
    int wv   = tid >> 6;
    int lane = tid & 63;
    double lsum = 0.0;
    for (int it = 0; it < 16; ++it) {
        size_t row = ((size_t)blockIdx.x * 16 + it) * 4 + wv;
        int f = (int)(row >> 12);
        float4 t = top2v[row];
        int c1 = __float_as_int(t.y), c2 = __float_as_int(t.w);
        const float* xr = x  + row * D;
        const float* w1 = wt + ((size_t)f * K + c1) * D;
        float4 xv = ((const float4*)xr)[lane];
        float4 a  = ((const float4*)w1)[lane];
        double s1 = 0.0;
#pragma unroll
        for (int j = 0; j < 4; ++j) {
            double d1 = (double)((const float*)&xv)[j] - (double)((const float*)&a)[j];
            s1 = fma(d1, d1, s1);
        }
#pragma unroll
        for (int off = 1; off < 64; off <<= 1) s1 += __shfl_xor(s1, off);

        float4 q = a;
        double sel = s1;
        if (t.z - t.x < 2e-3f) {   // ambiguous: exact-check candidate 2 (wave-uniform)
            const float* w2 = wt + ((size_t)f * K + c2) * D;
            float4 b = ((const float4*)w2)[lane];
            double s2 = 0.0;
#pragma unroll
            for (int j = 0; j < 4; ++j) {
                double d2 = (double)((const float*)&xv)[j] - (double)((const float*)&b)[j];
                s2 = fma(d2, d2, s2);
            }
#pragma unroll
            for (int off = 1; off < 64; off <<= 1) s2 += __shfl_xor(s2, off);
            bool pick2 = (s2 < s1) || (s2 == s1 && c2 < c1);
            if (pick2) { q = b; sel = s2; }
        }
        ((float4*)(out + row * D))[lane] = q;
        if (lane == 0) lsum += sel;
    }
    if (lane == 0) lpart[wv] = lsum;
    __syncthreads();
    if (tid == 0) {
        double tsum = lpart[0] + lpart[1] + lpart[2] + lpart[3];
        atomicAdd(lossAcc, tsum);
    }
}

__global__ void finish_loss(const double* __restrict__ lossAcc,
                            float* __restrict__ out_loss) {
    if (threadIdx.x == 0)
        *out_loss = (float)(0.25 * (*lossAcc) / ((double)F * (double)B * (double)D));
}

extern "C" void kernel_launch(void* const* d_in, const int* in_sizes, int n_in,
                              void* d_out, int out_size, void* d_ws, size_t ws_size,
                              hipStream_t stream) {
    const float* x = (const float*)d_in[0];   // [F,B,D]
    const float* w = (const float*)d_in[1];   // [F,D,K]
    float* out = (float*)d_out;

    ushort* whT   = (ushort*)((char*)d_ws + WHT_OFF);
    ushort* wlT   = (ushort*)((char*)d_ws + WLT_OFF);
    float*  wt    = (float*)((char*)d_ws + WT_OFF);
    float*  wsq   = (float*)((char*)d_ws + WSQ_OFF);
    float4* top2v = (float4*)((char*)d_ws + TOP2_OFF);
    double* lossAcc = (double*)((char*)d_ws + LOSS_OFF);

    init_kernel<<<dim3(64), 256, 0, stream>>>(wsq, lossAcc);
    transpose_split_w<<<dim3(K / 32, D / 32, F), dim3(32, 8), 0, stream>>>(w, wt, whT, wlT, wsq);
    gemm_mfma_top2<<<dim3((B / 64) * F), 512, 0, stream>>>(x, whT, wlT, wsq, top2v);
    refine_gather<<<dim3(F * B / 64), 256, 0, stream>>>(x, wt, top2v, out, lossAcc);
    finish_loss<<<1, 64, 0, stream>>>(lossAcc, out + (size_t)F * B * D);
}

// Round 6
// 500.690 us; speedup vs baseline: 1.2731x; 1.2731x over previous
//
#include <hip/hip_runtime.h>
#include <hip/hip_bf16.h>
#include <cstdint>
#include <cfloat>

#define F 16
#define B 4096
#define D 256
#define K 1024

typedef __attribute__((ext_vector_type(8))) short bf16x8;
typedef __attribute__((ext_vector_type(4))) float f32x4;

// ---- workspace layout (bytes) ----
// whP/wlP: packed MFMA-B-operand layout P[f][ntile(64)][ks(8)][lane(64)][8] bf16
#define WHP_OFF  0u            // 8388608
#define WLP_OFF  8388608u
#define WT_OFF   16777216u     // F*K*D fp32 transposed [f][k][d]
#define WSQ_OFF  33554432u     // F*K fp32
#define TOP2_OFF 33619968u     // F*B float4 {v1,i1,v2,i2} = 1 MB
#define LOSS_OFF 34668544u

// ---------------- init: zero wsq + loss ----------------
__global__ void init_kernel(float* __restrict__ wsq, double* __restrict__ lossAcc) {
    int i = blockIdx.x * 256 + threadIdx.x;
    if (i < F * K) wsq[i] = 0.f;
    if (i == 0) *lossAcc = 0.0;
}

// --- transpose w -> wt fp32 [f][k][d] + packed bf16 hi/lo + fused ||w_k||^2 ---
__global__ void transpose_split_w(const float* __restrict__ w, float* __restrict__ wt,
                                  ushort* __restrict__ whP, ushort* __restrict__ wlP,
                                  float* __restrict__ wsq) {
    __shared__ float sd[32][33];
    int f  = blockIdx.z;
    int k0 = blockIdx.x * 32;
    int d0 = blockIdx.y * 32;
    const float* wf = w + (size_t)f * D * K;
    size_t obase = (size_t)f * K * D;
    int tx = threadIdx.x, ty = threadIdx.y;
#pragma unroll
    for (int i = 0; i < 4; ++i) {
        int d = ty + i * 8;
        sd[d][tx] = wf[(size_t)(d0 + d) * K + (k0 + tx)];
    }
    __syncthreads();
#pragma unroll
    for (int i = 0; i < 4; ++i) {
        int k = ty + i * 8;
        float v = sd[tx][k];
        int n = k0 + k, d = d0 + tx;
        wt[obase + (size_t)n * D + d] = v;
        __hip_bfloat16 hb = __float2bfloat16(v);
        float hf = __bfloat162float(hb);
        __hip_bfloat16 lb = __float2bfloat16(v - hf);
        // packed index: [f][nt][ks][lane=quad*16+l15][j]
        size_t p = (((size_t)(f * 64 + (n >> 4)) * 8 + (d >> 5)) * 512)
                 + ((((d >> 3) & 3) * 16 + (n & 15)) * 8) + (d & 7);
        whP[p] = *(ushort*)&hb;
        wlP[p] = *(ushort*)&lb;
        float pw = v * v;
#pragma unroll
        for (int off = 1; off < 32; off <<= 1) pw += __shfl_xor(pw, off);
        if (tx == 0) atomicAdd(&wsq[f * K + n], pw);
    }
}

// ------------ MFMA split-bf16 GEMM + top-2, barrier-free, packed W ------------
// A (64 rows, full D, h+l) LDS seg-major: Ah [0,16384) Al [16384,32768) ushorts.
// W fragments: coalesced 1KB wave loads from the packed layout (L2-resident,
// f XCD-pinned so per-XCD W footprint = 2 MB < 4 MB L2).
__global__ __launch_bounds__(512, 4) void gemm_mfma_top2(
        const float* __restrict__ x,
        const ushort* __restrict__ whP, const ushort* __restrict__ wlP,
        const float* __restrict__ wsq, float4* __restrict__ top2v)
{
    __shared__ ushort lds[32768];   // 64 KiB -> 2 blocks/CU
    const int bid  = blockIdx.x;
    const int f    = (bid & 7) * 2 + (bid >> 9);   // XCD-pinned: bid%8 = XCD
    const int m0   = ((bid >> 3) & 63) * 64;
    const int tid  = threadIdx.x;
    const int lane = tid & 63;
    const int wave = tid >> 6;             // 0..7
    const int mw   = wave >> 2;            // 0..1 : 32-row half
    const int nw   = wave & 3;             // 0..3 : 32-col quarter of the 128-chunk
    const int quad = lane >> 4, l15 = lane & 15;

    const float* xb = x + ((size_t)f * B + m0) * D;

    // ---- prologue: read x fp32, split to bf16 h/l, store seg-major A to LDS
    {
        int row = tid & 63;
        int c4b = tid >> 6;                // 0..7
#pragma unroll
        for (int i = 0; i < 8; ++i) {
            int c4 = c4b + i * 8;          // 0..63 float4 within row
            float4 v = ((const float4*)xb)[row * 64 + c4];
            ushort4 h4, l4;
#pragma unroll
            for (int j = 0; j < 4; ++j) {
                float fv = ((const float*)&v)[j];
                __hip_bfloat16 hb = __float2bfloat16(fv);
                float hf = __bfloat162float(hb);
                __hip_bfloat16 lb = __float2bfloat16(fv - hf);
                ((ushort*)&h4)[j] = *(ushort*)&hb;
                ((ushort*)&l4)[j] = *(ushort*)&lb;
            }
            int seg = c4 >> 1, half = c4 & 1;
            int off = (seg * 64 + row) * 8 + half * 4;
            *(ushort4*)(lds + off)         = h4;
            *(ushort4*)(lds + 16384 + off) = l4;
        }
    }
    __syncthreads();   // the ONLY barrier before the merge

    float v1[8], v2[8];
    int   i1[8], i2[8];
#pragma unroll
    for (int s = 0; s < 8; ++s) {
        v1[s] = FLT_MAX; v2[s] = FLT_MAX; i1[s] = 0x7fffffff; i2[s] = 0x7fffffff;
    }

    for (int n0 = 0; n0 < K; n0 += 128) {
        f32x4 acc[2][2];
#pragma unroll
        for (int mt = 0; mt < 2; ++mt)
#pragma unroll
            for (int nt = 0; nt < 2; ++nt)
                acc[mt][nt] = (f32x4){0.f, 0.f, 0.f, 0.f};

        // per-wave packed W bases: ntile = f*64 + n0/16 + nw*2 (+nt)
        const size_t ntb = (size_t)(f * 64 + (n0 >> 4) + nw * 2);
        const ushort* ph0 = whP + ntb * 4096 + lane * 8;
        const ushort* ph1 = ph0 + 4096;
        const ushort* pl0 = wlP + ntb * 4096 + lane * 8;
        const ushort* pl1 = pl0 + 4096;

#pragma unroll
        for (int ks = 0; ks < 8; ++ks) {
            const int kofs = ks * 512;     // elements; byte offset ks*1024 (imm)
            bf16x8 bh0 = *(const bf16x8*)(ph0 + kofs);
            bf16x8 bl0 = *(const bf16x8*)(pl0 + kofs);
            bf16x8 bh1 = *(const bf16x8*)(ph1 + kofs);
            bf16x8 bl1 = *(const bf16x8*)(pl1 + kofs);
            bf16x8 ah[2], al[2];
#pragma unroll
            for (int mt = 0; mt < 2; ++mt) {
                int off = ((ks * 4 + quad) * 64 + mw * 32 + mt * 16 + l15) * 8;
                ah[mt] = *(const bf16x8*)(lds + off);
                al[mt] = *(const bf16x8*)(lds + 16384 + off);
            }
#pragma unroll
            for (int mt = 0; mt < 2; ++mt) {
                acc[mt][0] = __builtin_amdgcn_mfma_f32_16x16x32_bf16(ah[mt], bh0, acc[mt][0], 0, 0, 0);
                acc[mt][0] = __builtin_amdgcn_mfma_f32_16x16x32_bf16(ah[mt], bl0, acc[mt][0], 0, 0, 0);
                acc[mt][0] = __builtin_amdgcn_mfma_f32_16x16x32_bf16(al[mt], bh0, acc[mt][0], 0, 0, 0);
                acc[mt][1] = __builtin_amdgcn_mfma_f32_16x16x32_bf16(ah[mt], bh1, acc[mt][1], 0, 0, 0);
                acc[mt][1] = __builtin_amdgcn_mfma_f32_16x16x32_bf16(ah[mt], bl1, acc[mt][1], 0, 0, 0);
                acc[mt][1] = __builtin_amdgcn_mfma_f32_16x16x32_bf16(al[mt], bh1, acc[mt][1], 0, 0, 0);
            }
        }

        // epilogue: fold 128-column chunk into per-lane top-2
#pragma unroll
        for (int nt = 0; nt < 2; ++nt) {
            int ng = n0 + nw * 32 + nt * 16 + l15;
            float wq = wsq[f * K + ng];
#pragma unroll
            for (int mt = 0; mt < 2; ++mt) {
#pragma unroll
                for (int r = 0; r < 4; ++r) {
                    int s = mt * 4 + r;
                    float sc = fmaf(-2.f, acc[mt][nt][r], wq);
                    if (sc < v1[s]) { v2[s] = v1[s]; i2[s] = i1[s]; v1[s] = sc; i1[s] = ng; }
                    else if (sc < v2[s]) { v2[s] = sc; i2[s] = ng; }
                }
            }
        }
    }

    // cross-lane merge among the 16 l15 lanes (fixed quad)
#pragma unroll
    for (int s = 0; s < 8; ++s) {
#pragma unroll
        for (int off = 1; off < 16; off <<= 1) {
            float ov1 = __shfl_xor(v1[s], off);
            int   oi1 = __shfl_xor(i1[s], off);
            float ov2 = __shfl_xor(v2[s], off);
            int   oi2 = __shfl_xor(i2[s], off);
            bool sw = (ov1 < v1[s]) || (ov1 == v1[s] && oi1 < i1[s]);
            float a1 = sw ? ov1 : v1[s]; int a1i = sw ? oi1 : i1[s];
            float b1 = sw ? v1[s] : ov1; int b1i = sw ? i1[s] : oi1;
            float a2 = sw ? ov2 : v2[s]; int a2i = sw ? oi2 : i2[s];
            bool rp = (b1 < a2) || (b1 == a2 && b1i < a2i);
            v1[s] = a1;            i1[s] = a1i;
            v2[s] = rp ? b1 : a2;  i2[s] = rp ? b1i : a2i;
        }
    }

    // cross-wave (nw 0..3) merge via LDS (A region reusable after barrier)
    __syncthreads();
    float4* mrg = (float4*)lds;            // [64 rows][4 nw] float4
    if (l15 == 0) {
#pragma unroll
        for (int mt = 0; mt < 2; ++mt)
#pragma unroll
            for (int r = 0; r < 4; ++r) {
                int s = mt * 4 + r;
                int rl = mw * 32 + mt * 16 + quad * 4 + r;
                mrg[rl * 4 + nw] = make_float4(v1[s], __int_as_float(i1[s]),
                                               v2[s], __int_as_float(i2[s]));
            }
    }
    __syncthreads();
    if (nw == 0 && l15 == 0) {
#pragma unroll
        for (int mt = 0; mt < 2; ++mt)
#pragma unroll
            for (int r = 0; r < 4; ++r) {
                int s = mt * 4 + r;
                int rl = mw * 32 + mt * 16 + quad * 4 + r;
                float bv1 = v1[s], bv2 = v2[s];
                int   bi1 = i1[s], bi2 = i2[s];
#pragma unroll
                for (int q = 1; q < 4; ++q) {
                    float4 tq = mrg[rl * 4 + q];
                    float ov1 = tq.x, ov2 = tq.z;
                    int   oi1 = __float_as_int(tq.y), oi2 = __float_as_int(tq.w);
                    bool sw = (ov1 < bv1) || (ov1 == bv1 && oi1 < bi1);
                    float a1 = sw ? ov1 : bv1; int a1i = sw ? oi1 : bi1;
                    float b1 = sw ? bv1 : ov1; int b1i = sw ? bi1 : oi1;
                    float a2 = sw ? ov2 : bv2; int a2i = sw ? oi2 : bi2;
                    bool rp = (b1 < a2) || (b1 == a2 && b1i < a2i);
                    bv1 = a1; bi1 = a1i;
                    bv2 = rp ? b1 : a2; bi2 = rp ? b1i : a2i;
                }
                top2v[(size_t)f * B + m0 + rl] =
                    make_float4(bv1, __int_as_float(bi1), bv2, __int_as_float(bi2));
            }
    }
}

// -------- fp64 refine + gather + loss; skip 2nd gather when gap is safe --------
__global__ __launch_bounds__(256) void refine_gather(
        const float* __restrict__ x, const float* __restrict__ wt,
        const float4* __restrict__ top2v, float* __restrict__ out,
        double* __restrict__ lossAcc) {
    __shared__ double lpart[4];
    int tid  = threadIdx.x;
    int wv   = tid >> 6;
    int lane = tid & 63;
    double lsum = 0.0;
    for (int it = 0; it < 16; ++it) {
        size_t row = ((size_t)blockIdx.x * 16 + it) * 4 + wv;
        int f = (int)(row >> 12);
        float4 t = top2v[row];
        int c1 = __float_as_int(t.y), c2 = __float_as_int(t.w);
        const float* xr = x  + row * D;
        const float* w1 = wt + ((size_t)f * K + c1) * D;
        float4 xv = ((const float4*)xr)[lane];
        float4 a  = ((const float4*)w1)[lane];
        double s1 = 0.0;
#pragma unroll
        for (int j = 0; j < 4; ++j) {
            double d1 = (double)((const float*)&xv)[j] - (double)((const float*)&a)[j];
            s1 = fma(d1, d1, s1);
        }
#pragma unroll
        for (int off = 1; off < 64; off <<= 1) s1 += __shfl_xor(s1, off);

        float4 q = a;
        double sel = s1;
        if (t.z - t.x < 2e-3f) {   // ambiguous: exact-check candidate 2 (wave-uniform)
            const float* w2 = wt + ((size_t)f * K + c2) * D;
            float4 b = ((const float4*)w2)[lane];
            double s2 = 0.0;
#pragma unroll
            for (int j = 0; j < 4; ++j) {
                double d2 = (double)((const float*)&xv)[j] - (double)((const float*)&b)[j];
                s2 = fma(d2, d2, s2);
            }
#pragma unroll
            for (int off = 1; off < 64; off <<= 1) s2 += __shfl_xor(s2, off);
            bool pick2 = (s2 < s1) || (s2 == s1 && c2 < c1);
            if (pick2) { q = b; sel = s2; }
        }
        ((float4*)(out + row * D))[lane] = q;
        if (lane == 0) lsum += sel;
    }
    if (lane == 0) lpart[wv] = lsum;
    __syncthreads();
    if (tid == 0) {
        double tsum = lpart[0] + lpart[1] + lpart[2] + lpart[3];
        atomicAdd(lossAcc, tsum);
    }
}

__global__ void finish_loss(const double* __restrict__ lossAcc,
                            float* __restrict__ out_loss) {
    if (threadIdx.x == 0)
        *out_loss = (float)(0.25 * (*lossAcc) / ((double)F * (double)B * (double)D));
}

extern "C" void kernel_launch(void* const* d_in, const int* in_sizes, int n_in,
                              void* d_out, int out_size, void* d_ws, size_t ws_size,
                              hipStream_t stream) {
    const float* x = (const float*)d_in[0];   // [F,B,D]
    const float* w = (const float*)d_in[1];   // [F,D,K]
    float* out = (float*)d_out;

    ushort* whP   = (ushort*)((char*)d_ws + WHP_OFF);
    ushort* wlP   = (ushort*)((char*)d_ws + WLP_OFF);
    float*  wt    = (float*)((char*)d_ws + WT_OFF);
    float*  wsq   = (float*)((char*)d_ws + WSQ_OFF);
    float4* top2v = (float4*)((char*)d_ws + TOP2_OFF);
    double* lossAcc = (double*)((char*)d_ws + LOSS_OFF);

    init_kernel<<<dim3(64), 256, 0, stream>>>(wsq, lossAcc);
    transpose_split_w<<<dim3(K / 32, D / 32, F), dim3(32, 8), 0, stream>>>(w, wt, whP, wlP, wsq);
    gemm_mfma_top2<<<dim3((B / 64) * F), 512, 0, stream>>>(x, whP, wlP, wsq, top2v);
    refine_gather<<<dim3(F * B / 64), 256, 0, stream>>>(x, wt, top2v, out, lossAcc);
    finish_loss<<<1, 64, 0, stream>>>(lossAcc, out + (size_t)F * B * D);
}